// Round 6
// baseline (89.811 us; speedup 1.0000x reference)
//
#include <hip/hip_runtime.h>

#define NB 4
#define NS 1024
#define NH 16
#define ND 64

typedef __attribute__((ext_vector_type(8))) short bf16x8;
typedef __attribute__((ext_vector_type(4))) short bf16x4;
typedef __attribute__((ext_vector_type(4))) float f32x4;

static __device__ __forceinline__ short f2bf(float x) {
  __bf16 h = (__bf16)x;
  return __builtin_bit_cast(short, h);
}
static __device__ __forceinline__ float bf2f(short s) {
  unsigned u = ((unsigned)(unsigned short)s) << 16;
  return __builtin_bit_cast(float, u);
}

static __device__ __forceinline__ f32x4 mfma16_bf16(bf16x4 a, bf16x4 b, f32x4 c) {
#if __has_builtin(__builtin_amdgcn_mfma_f32_16x16x16bf16_1k)
  return __builtin_amdgcn_mfma_f32_16x16x16bf16_1k(a, b, c, 0, 0, 0);
#else
  f32x4 d;
  asm("v_mfma_f32_16x16x16_bf16 %0, %1, %2, %3" : "=v"(d) : "v"(a), "v"(b), "v"(c));
  return d;
#endif
}

__global__ __launch_bounds__(256, 2)
void fsa_fwd(const float* __restrict__ qkv,
             const float* __restrict__ bias,
             float* __restrict__ out)
{
  // XCD-chunked swizzle, batch-fastest logical order (round-3, kept).
  const int hw = blockIdx.x;
  const int lg = ((hw & 7) << 7) | (hw >> 3);
  const int b  = lg & 3;
  const int qt = (lg >> 2) & 15;
  const int h  = lg >> 6;

  const int tid  = threadIdx.x;
  const int w    = tid >> 6;
  const int lane = tid & 63;
  const int lo   = lane & 15;
  const int hi   = lane >> 4;
  const int q0   = qt * 64;

  __shared__ __attribute__((aligned(16))) short Ksh[64 * 64];   // [t][d] XOR-swizzled rows
  __shared__ __attribute__((aligned(16))) short VTsh[64 * 64];  // [d][t] packed-pair XOR-swizzled

  // ---- Q fragments (now the B-operand of swapped QK^T; identical element layout) ----
  bf16x8 qf[2];
  {
    const int qs = q0 + w * 16 + lo;
    const float* qp = qkv + ((size_t)(b * NS + qs) * 3) * (NH * ND) + h * ND + hi * 8;
    #pragma unroll
    for (int f = 0; f < 2; ++f) {
      float4 x0 = *(const float4*)(qp + f * 32);
      float4 x1 = *(const float4*)(qp + f * 32 + 4);
      float v[8] = {x0.x, x0.y, x0.z, x0.w, x1.x, x1.y, x1.z, x1.w};
      #pragma unroll
      for (int j = 0; j < 8; ++j) qf[f][j] = f2bf(v[j] * 0.125f);
    }
  }

  const size_t tstr = 3 * NH * ND;
  const float* kgp = qkv + (size_t)b * NS * tstr + 1 * NH * ND + h * ND;
  const float* vgp = qkv + (size_t)b * NS * tstr + 2 * NH * ND + h * ND;

  const int krow = tid >> 2;          // 0..63
  const int kd   = (tid & 3) * 16;    // 16 floats
  const int vrow = (tid & 31) * 2;    // t pair
  const int vd   = (tid >> 5) * 8;    // 8 d's

  // bias: lane owns q-row q0+w*16+lo; per subtile tt a float4 over t = t0+tt*16+hi*4..+3
  const float* bbT = bias + (size_t)h * NS * NS + (size_t)(q0 + w * 16 + lo) * NS + hi * 4;

  float psum = 0.f;
  f32x4 oaccT[4];
  #pragma unroll
  for (int dt = 0; dt < 4; ++dt) { f32x4 z = {0.f, 0.f, 0.f, 0.f}; oaccT[dt] = z; }

  // prefetch regs: K/V hold tile t (consumed by STAGE at iter t); brT holds bias(t).
  float4 ka, kc, ke, kg4, va0, va1, vb0, vb1;
  float4 brT[4];

#define LOAD_KV(T0) do { \
    const float* src_ = kgp + (size_t)((T0) + krow) * tstr + kd; \
    ka  = ((const float4*)src_)[0]; kc  = ((const float4*)src_)[1]; \
    ke  = ((const float4*)src_)[2]; kg4 = ((const float4*)src_)[3]; \
    const float* s0_ = vgp + (size_t)((T0) + vrow) * tstr + vd; \
    const float* s1_ = s0_ + tstr; \
    va0 = ((const float4*)s0_)[0]; va1 = ((const float4*)s0_)[1]; \
    vb0 = ((const float4*)s1_)[0]; vb1 = ((const float4*)s1_)[1]; \
  } while (0)

#define LOAD_BIAS(T0) do { \
    _Pragma("unroll") \
    for (int tt_ = 0; tt_ < 4; ++tt_) \
      brT[tt_] = *(const float4*)(bbT + (T0) + tt_ * 16); \
  } while (0)

#define STAGE() do { \
    bf16x8 w0_, w1_; \
    { \
      float v_[16] = {ka.x,ka.y,ka.z,ka.w, kc.x,kc.y,kc.z,kc.w, \
                      ke.x,ke.y,ke.z,ke.w, kg4.x,kg4.y,kg4.z,kg4.w}; \
      _Pragma("unroll") \
      for (int j_ = 0; j_ < 8; ++j_) { w0_[j_] = f2bf(v_[j_]); w1_[j_] = f2bf(v_[8+j_]); } \
    } \
    { \
      const int base_ = krow * 64 + kd; \
      const int sw_ = (krow & 7) << 3; \
      *(bf16x8*)&Ksh[(base_    ) ^ sw_] = w0_; \
      *(bf16x8*)&Ksh[(base_ + 8) ^ sw_] = w1_; \
    } \
    { \
      float r0_[8] = {va0.x,va0.y,va0.z,va0.w, va1.x,va1.y,va1.z,va1.w}; \
      float r1_[8] = {vb0.x,vb0.y,vb0.z,vb0.w, vb1.x,vb1.y,vb1.z,vb1.w}; \
      unsigned* vt_ = (unsigned*)VTsh; \
      _Pragma("unroll") \
      for (int j_ = 0; j_ < 8; ++j_) { \
        unsigned pk_ = (unsigned)(unsigned short)f2bf(r0_[j_]) | \
                       ((unsigned)(unsigned short)f2bf(r1_[j_]) << 16); \
        const int R_ = vd + j_; \
        vt_[R_ * 32 + ((vrow >> 1) ^ ((R_ & 7) << 2))] = pk_; \
      } \
    } \
  } while (0)

  // ---- prologue ----
  LOAD_KV(0);
  LOAD_BIAS(0);

  #pragma unroll 1
  for (int t = 0; t < 16; ++t) {
    __syncthreads();                 // protect: prior compute's LDS reads done
    STAGE();                         // ds_write K,VT (tile t)
    if (t < 15) LOAD_KV((t + 1) * 64);   // next tile flies under compute
    __syncthreads();                 // tile t visible

    // S^T acc init = bias^T - 8 (constant-shift softmax)
    f32x4 sacc[4];
    #pragma unroll
    for (int tt = 0; tt < 4; ++tt) {
      #pragma unroll
      for (int r = 0; r < 4; ++r) sacc[tt][r] = brT[tt][r] - 8.f;
    }
    if (t < 15) LOAD_BIAS((t + 1) * 64);

    __builtin_amdgcn_s_setprio(1);
    #pragma unroll
    for (int tt = 0; tt < 4; ++tt) {
      // swapped QK^T: A = K rows (t-local = tt*16+lo), B = Q
      const int kr  = tt * 16 + lo;
      const int ksw = (kr & 7) << 3;
      bf16x8 a0 = *(const bf16x8*)&Ksh[(kr * 64      + hi * 8) ^ ksw];
      bf16x8 a1 = *(const bf16x8*)&Ksh[(kr * 64 + 32 + hi * 8) ^ ksw];
      sacc[tt] = __builtin_amdgcn_mfma_f32_16x16x32_bf16(a0, qf[0], sacc[tt], 0, 0, 0);
      sacc[tt] = __builtin_amdgcn_mfma_f32_16x16x32_bf16(a1, qf[1], sacc[tt], 0, 0, 0);

      // P^T = exp(S^T): lane holds P^T[t=tt*16+hi*4+r][q=lo] -> PV B-frag directly
      bf16x4 pfrag;
      #pragma unroll
      for (int r = 0; r < 4; ++r) {
        float p = __expf(sacc[tt][r]);
        short pb = f2bf(p);
        psum += bf2f(pb);            // denominator uses the same rounded P
        pfrag[r] = pb;
      }

      // PV: O^T[d][q] += V^T x P^T, one 16x16x16 per d-tile
      #pragma unroll
      for (int dt = 0; dt < 4; ++dt) {
        const int R = dt * 16 + lo;
        const int pidx = (tt * 8 + hi * 2) ^ ((R & 7) << 2);
        bf16x4 vt = *(const bf16x4*)&((const unsigned*)VTsh)[R * 32 + pidx];
        oaccT[dt] = mfma16_bf16(vt, pfrag, oaccT[dt]);
      }
    }
    __builtin_amdgcn_s_setprio(0);
  }

#undef STAGE
#undef LOAD_BIAS
#undef LOAD_KV

  // ---- denominator: sum over the 4 hi-groups (t-slices) ----
  psum += __shfl_xor(psum, 16, 64);
  psum += __shfl_xor(psum, 32, 64);
  const float inv = 1.f / psum;

  // ---- epilogue: out[b][q0+w*16+lo][h][dt*16+hi*4+r], float4 per dt ----
  float* ob = out + ((size_t)(b * NS + q0 + w * 16 + lo) * NH + h) * ND + hi * 4;
  #pragma unroll
  for (int dt = 0; dt < 4; ++dt) {
    float4 v;
    v.x = oaccT[dt][0] * inv;
    v.y = oaccT[dt][1] * inv;
    v.z = oaccT[dt][2] * inv;
    v.w = oaccT[dt][3] * inv;
    *(float4*)(ob + dt * 16) = v;
  }
}

extern "C" void kernel_launch(void* const* d_in, const int* in_sizes, int n_in,
                              void* d_out, int out_size, void* d_ws, size_t ws_size,
                              hipStream_t stream) {
  const float* qkv  = (const float*)d_in[0];
  const float* bias = (const float*)d_in[1];
  float* out = (float*)d_out;
  dim3 grid(NB * NH * (NS / 64));
  fsa_fwd<<<grid, 256, 0, stream>>>(qkv, bias, out);
}

// Round 7
// 84.547 us; speedup vs baseline: 1.0623x; 1.0623x over previous
//
#include <hip/hip_runtime.h>

#define NB 4
#define NS 1024
#define NH 16
#define ND 64

#define OFF_O ((size_t)NB * NS * NH * ND)   // 4194304 floats per half
#define N_BSH (NB * NS * NH)                // 65536

typedef __attribute__((ext_vector_type(8))) short bf16x8;
typedef __attribute__((ext_vector_type(4))) float f32x4;

static __device__ __forceinline__ short f2bf(float x) {
  __bf16 h = (__bf16)x;
  return __builtin_bit_cast(short, h);
}
static __device__ __forceinline__ float bf2f(short s) {
  unsigned u = ((unsigned)(unsigned short)s) << 16;
  return __builtin_bit_cast(float, u);
}

__global__ __launch_bounds__(256, 2)
void fsa_fwd(const float* __restrict__ qkv,
             const float* __restrict__ bias,
             float* __restrict__ out,
             float* __restrict__ opart,
             float* __restrict__ psums,
             int split)
{
  // XCD-chunked swizzle (generic in grid size), batch-adjacent logical order.
  const int hw  = blockIdx.x;
  const int cpx = gridDim.x >> 3;
  const int lg  = (hw & 7) * cpx + (hw >> 3);
  int b, qt, h, half, tbeg, tcnt;
  if (split == 2) {
    half = lg & 1; b = (lg >> 1) & 3; qt = (lg >> 3) & 15; h = lg >> 7;
    tbeg = half * 512; tcnt = 8;
  } else {
    half = 0; b = lg & 3; qt = (lg >> 2) & 15; h = lg >> 6;
    tbeg = 0; tcnt = 16;
  }

  const int tid  = threadIdx.x;
  const int w    = tid >> 6;
  const int lane = tid & 63;
  const int lo   = lane & 15;
  const int hi   = lane >> 4;
  const int q0   = qt * 64;

  __shared__ __attribute__((aligned(16))) short Ksh[64 * 64];   // [t][d] XOR-swizzled rows
  __shared__ __attribute__((aligned(16))) short VTsh[64 * 64];  // [d][t] packed-pair XOR-swizzled
  __shared__ __attribute__((aligned(16))) short Psh[4][16 * 64];// per-wave P strip

  // ---- Q fragments (A-operand), pre-scaled by 1/8 ----
  bf16x8 qf[2];
  {
    const int qs = q0 + w * 16 + lo;
    const float* qp = qkv + ((size_t)(b * NS + qs) * 3) * (NH * ND) + h * ND + hi * 8;
    #pragma unroll
    for (int f = 0; f < 2; ++f) {
      float4 x0 = *(const float4*)(qp + f * 32);
      float4 x1 = *(const float4*)(qp + f * 32 + 4);
      float v[8] = {x0.x, x0.y, x0.z, x0.w, x1.x, x1.y, x1.z, x1.w};
      #pragma unroll
      for (int j = 0; j < 8; ++j) qf[f][j] = f2bf(v[j] * 0.125f);
    }
  }

  const size_t tstr = 3 * NH * ND;
  const float* kgp = qkv + (size_t)b * NS * tstr + 1 * NH * ND + h * ND;
  const float* vgp = qkv + (size_t)b * NS * tstr + 2 * NH * ND + h * ND;

  const int krow = tid >> 2;          // 0..63
  const int kd   = (tid & 3) * 16;    // 16 floats
  const int vrow = (tid & 31) * 2;    // t pair
  const int vd   = (tid >> 5) * 8;    // 8 d's

  const float* bb = bias + (size_t)h * NS * NS + (size_t)(q0 + w * 16 + hi * 4) * NS + lo;

  float psum[4] = {0.f, 0.f, 0.f, 0.f};
  f32x4 oacc[4];
  #pragma unroll
  for (int dt = 0; dt < 4; ++dt) { f32x4 z = {0.f, 0.f, 0.f, 0.f}; oacc[dt] = z; }

  // prefetch regs: K/V hold tile t entering iter t (consumed by STAGE);
  // br holds bias(t) entering iter t.
  float4 ka, kc, ke, kg4, va0, va1, vb0, vb1;
  float br[4][4];

#define LOAD_KV(T0) do { \
    const float* src_ = kgp + (size_t)((T0) + krow) * tstr + kd; \
    ka  = ((const float4*)src_)[0]; kc  = ((const float4*)src_)[1]; \
    ke  = ((const float4*)src_)[2]; kg4 = ((const float4*)src_)[3]; \
    const float* s0_ = vgp + (size_t)((T0) + vrow) * tstr + vd; \
    const float* s1_ = s0_ + tstr; \
    va0 = ((const float4*)s0_)[0]; va1 = ((const float4*)s0_)[1]; \
    vb0 = ((const float4*)s1_)[0]; vb1 = ((const float4*)s1_)[1]; \
  } while (0)

#define LOAD_BIAS(T0) do { \
    _Pragma("unroll") \
    for (int r_ = 0; r_ < 4; ++r_) { \
      _Pragma("unroll") \
      for (int tt_ = 0; tt_ < 4; ++tt_) \
        br[r_][tt_] = bb[(size_t)r_ * NS + (T0) + tt_ * 16]; \
    } \
  } while (0)

#define STAGE() do { \
    bf16x8 w0_, w1_; \
    { \
      float v_[16] = {ka.x,ka.y,ka.z,ka.w, kc.x,kc.y,kc.z,kc.w, \
                      ke.x,ke.y,ke.z,ke.w, kg4.x,kg4.y,kg4.z,kg4.w}; \
      _Pragma("unroll") \
      for (int j_ = 0; j_ < 8; ++j_) { w0_[j_] = f2bf(v_[j_]); w1_[j_] = f2bf(v_[8+j_]); } \
    } \
    { \
      const int base_ = krow * 64 + kd; \
      const int sw_ = (krow & 7) << 3; \
      *(bf16x8*)&Ksh[(base_    ) ^ sw_] = w0_; \
      *(bf16x8*)&Ksh[(base_ + 8) ^ sw_] = w1_; \
    } \
    { \
      float r0_[8] = {va0.x,va0.y,va0.z,va0.w, va1.x,va1.y,va1.z,va1.w}; \
      float r1_[8] = {vb0.x,vb0.y,vb0.z,vb0.w, vb1.x,vb1.y,vb1.z,vb1.w}; \
      unsigned* vt_ = (unsigned*)VTsh; \
      _Pragma("unroll") \
      for (int j_ = 0; j_ < 8; ++j_) { \
        unsigned pk_ = (unsigned)(unsigned short)f2bf(r0_[j_]) | \
                       ((unsigned)(unsigned short)f2bf(r1_[j_]) << 16); \
        const int R_ = vd + j_; \
        vt_[R_ * 32 + ((vrow >> 1) ^ ((R_ & 7) << 2))] = pk_; \
      } \
    } \
  } while (0)

  // ---- prologue: tile tbeg regs + bias ----
  LOAD_KV(tbeg);
  LOAD_BIAS(tbeg);

  #pragma unroll 1
  for (int it = 0; it < tcnt; ++it) {
    const int t0 = tbeg + it * 64;

    __syncthreads();                     // prior compute's LDS reads done
    STAGE();                             // ds_write tile t (regs from last iter)
    if (it + 1 < tcnt) LOAD_KV(t0 + 64); // next tile flies under compute
    __syncthreads();                     // tile t visible

    // S acc init = bias - 8 (constant-shift softmax)
    f32x4 sacc[4];
    #pragma unroll
    for (int tt = 0; tt < 4; ++tt) {
      #pragma unroll
      for (int r = 0; r < 4; ++r) sacc[tt][r] = br[r][tt] - 8.f;
    }
    if (it + 1 < tcnt) LOAD_BIAS(t0 + 64);

    __builtin_amdgcn_s_setprio(1);
    // ---- QK^T: 8 MFMAs, long independent runs (R3 body) ----
    #pragma unroll
    for (int tt = 0; tt < 4; ++tt) {
      const int kr = tt * 16 + lo;
      const int ksw = (kr & 7) << 3;
      bf16x8 k0 = *(const bf16x8*)&Ksh[(kr * 64      + hi * 8) ^ ksw];
      bf16x8 k1 = *(const bf16x8*)&Ksh[(kr * 64 + 32 + hi * 8) ^ ksw];
      sacc[tt] = __builtin_amdgcn_mfma_f32_16x16x32_bf16(qf[0], k0, sacc[tt], 0, 0, 0);
      sacc[tt] = __builtin_amdgcn_mfma_f32_16x16x32_bf16(qf[1], k1, sacc[tt], 0, 0, 0);
    }

    // ---- P = exp(s), per-lane psum, per-wave P strip ----
    short* pw = Psh[w];
    #pragma unroll
    for (int r = 0; r < 4; ++r) {
      const int row = hi * 4 + r;
      const int sw = (row & 7) << 3;
      #pragma unroll
      for (int tt = 0; tt < 4; ++tt) {
        float p = __expf(sacc[tt][r]);
        short pb = f2bf(p);
        psum[r] += bf2f(pb);
        pw[row * 64 + ((tt * 16 + lo) ^ sw)] = pb;
      }
    }
    asm volatile("s_waitcnt lgkmcnt(0)" ::: "memory");

    // ---- PV ----
    bf16x8 pf0, pf1;
    {
      const int psw = (lo & 7) << 3;
      pf0 = *(const bf16x8*)&pw[lo * 64 + ((     hi * 8) ^ psw)];
      pf1 = *(const bf16x8*)&pw[lo * 64 + ((32 + hi * 8) ^ psw)];
    }
    #pragma unroll
    for (int dt = 0; dt < 4; ++dt) {
      const int vr = dt * 16 + lo;
      const int vsw = (vr & 7) << 3;
      bf16x8 v0 = *(const bf16x8*)&VTsh[vr * 64 + ((     hi * 8) ^ vsw)];
      bf16x8 v1 = *(const bf16x8*)&VTsh[vr * 64 + ((32 + hi * 8) ^ vsw)];
      oacc[dt] = __builtin_amdgcn_mfma_f32_16x16x32_bf16(pf0, v0, oacc[dt], 0, 0, 0);
      oacc[dt] = __builtin_amdgcn_mfma_f32_16x16x32_bf16(pf1, v1, oacc[dt], 0, 0, 0);
    }
    __builtin_amdgcn_s_setprio(0);
  }

#undef STAGE
#undef LOAD_BIAS
#undef LOAD_KV

  // ---- row-sum reduction over the 16 lo lanes ----
  #pragma unroll
  for (int r = 0; r < 4; ++r) {
    psum[r] += __shfl_xor(psum[r], 1, 64);
    psum[r] += __shfl_xor(psum[r], 2, 64);
    psum[r] += __shfl_xor(psum[r], 4, 64);
    psum[r] += __shfl_xor(psum[r], 8, 64);
  }

  const size_t rowbase = (size_t)(b * NS + q0 + w * 16 + hi * 4);
  if (split == 2) {
    // ---- write unnormalized partial + psum to workspace ----
    float* op = opart + (size_t)half * OFF_O + (rowbase * NH + h) * ND + lo;
    #pragma unroll
    for (int r = 0; r < 4; ++r)
      #pragma unroll
      for (int dt = 0; dt < 4; ++dt)
        op[(size_t)r * NH * ND + dt * 16] = oacc[dt][r];
    if (lo == 0) {
      float* lp = psums + (size_t)half * N_BSH;
      #pragma unroll
      for (int r = 0; r < 4; ++r)
        lp[(rowbase + r) * NH + h] = psum[r];
    }
  } else {
    float* ob = out + (rowbase * NH + h) * ND + lo;
    #pragma unroll
    for (int r = 0; r < 4; ++r) {
      float inv = 1.f / psum[r];
      #pragma unroll
      for (int dt = 0; dt < 4; ++dt)
        ob[(size_t)r * NH * ND + dt * 16] = oacc[dt][r] * inv;
    }
  }
}

__global__ __launch_bounds__(256)
void fsa_combine(const float* __restrict__ opart,
                 const float* __restrict__ psums,
                 float* __restrict__ out)
{
  const int gid = blockIdx.x * 256 + threadIdx.x;   // one float4 each; BSHD/4 total
  const int bsh = gid >> 4;                          // 16 float4 per (b,s,h)
  const float l = psums[bsh] + psums[N_BSH + bsh];
  const float inv = 1.f / l;
  float4 a = ((const float4*)opart)[gid];
  float4 c = ((const float4*)(opart + OFF_O))[gid];
  float4 o;
  o.x = (a.x + c.x) * inv;
  o.y = (a.y + c.y) * inv;
  o.z = (a.z + c.z) * inv;
  o.w = (a.w + c.w) * inv;
  ((float4*)out)[gid] = o;
}

extern "C" void kernel_launch(void* const* d_in, const int* in_sizes, int n_in,
                              void* d_out, int out_size, void* d_ws, size_t ws_size,
                              hipStream_t stream) {
  const float* qkv  = (const float*)d_in[0];
  const float* bias = (const float*)d_in[1];
  float* out = (float*)d_out;

  const size_t need = (2 * OFF_O + 2 * (size_t)N_BSH) * sizeof(float);  // ~33 MB
  const int split = (ws_size >= need) ? 2 : 1;
  float* opart = (float*)d_ws;
  float* psums = (float*)d_ws + 2 * OFF_O;

  dim3 grid(split == 2 ? 2048 : 1024);
  fsa_fwd<<<grid, 256, 0, stream>>>(qkv, bias, out, opart, psums, split);
  if (split == 2) {
    const int n4 = NB * NS * NH * ND / 4;            // 1048576
    fsa_combine<<<n4 / 256, 256, 0, stream>>>(opart, psums, out);
  }
}